// Round 4
// baseline (171.117 us; speedup 1.0000x reference)
//
#include <hip/hip_runtime.h>

#define HD  64      // HIDDEN_DIM
#define NE  512     // N_EMBEDS
#define HW  1024    // 32*32 spatial positions per batch image

// ---------------------------------------------------------------------------
// Prep kernel (72 blocks x 64 threads):
//  blocks 0..63 : pack octet o: ep[o][c][j] = -2 * e[o*8+j][c]   (o = k>>3)
//                 -2 fold is bit-exact: pow2 scaling commutes with fp32
//                 rounding, so main's d = (xsq+esq) + a == (xsq+esq) - 2a.
//  blocks 64..71: esq[k] = np.sum(e[k]*e[k]) with numpy's pairwise-8 order,
//                 no contraction. Verified absmax == 0.0 in R1-R3.
// ---------------------------------------------------------------------------
__global__ __launch_bounds__(64) void vq_prep_kernel(const float* __restrict__ e,
                                                     float* __restrict__ ep,
                                                     float* __restrict__ esq) {
  const int blk = blockIdx.x;
  if (blk < 64) {
    const int c = threadIdx.x;                  // 0..63
    #pragma unroll
    for (int j = 0; j < 8; ++j) {
      ep[blk * 512 + c * 8 + j] = -2.0f * e[(blk * 8 + j) * HD + c];
    }
  } else {
    const int k = (blk - 64) * 64 + threadIdx.x;  // 0..511
    const float4* __restrict__ rowv = reinterpret_cast<const float4*>(e + k * HD);
    float row[HD];
    #pragma unroll
    for (int i = 0; i < 16; ++i) {
      const float4 v = rowv[i];
      row[4 * i + 0] = v.x; row[4 * i + 1] = v.y;
      row[4 * i + 2] = v.z; row[4 * i + 3] = v.w;
    }
    float result;
    {
      #pragma clang fp contract(off)
      float r[8];
      #pragma unroll
      for (int j = 0; j < 8; ++j) r[j] = row[j] * row[j];
      #pragma unroll
      for (int i = 8; i < HD; i += 8) {
        #pragma unroll
        for (int j = 0; j < 8; ++j) r[j] = r[j] + row[i + j] * row[i + j];
      }
      result = ((r[0] + r[1]) + (r[2] + r[3])) + ((r[4] + r[5]) + (r[6] + r[7]));
    }
    esq[k] = result;
  }
}

// ---------------------------------------------------------------------------
// Main kernel R4: 1024 blocks x 512 threads (8 waves). Block = 64 positions
// (lane = position, shared by all waves); wave w covers codes
// [w*64, w*64+64) = octets [w*8, w*8+8).
//
// x lives in LDS as xs[c][lane] (conflict-free, ds_read_b32 with immediate
// offsets off one base) instead of VGPRs -- R2/R3 showed the register
// allocator refuses to keep xv[64] resident (VGPR stuck at 52, half the
// VALU issue was overhead). Low VGPR use + 512-thread blocks gives
// 32 waves/CU (vs 16), hiding the ep-load latency via co-issue.
// ep streams as two uniform float4 loads per c (immediate offsets from a
// per-octet base, or s_loads if uniformity analysis fires).
// ---------------------------------------------------------------------------
__global__ __launch_bounds__(512, 8) void vq_main_kernel(const float* __restrict__ x,
                                                         const float* __restrict__ ep,
                                                         const float* __restrict__ esq,
                                                         const float* __restrict__ e,
                                                         float* __restrict__ out) {
  __shared__ float xs[64 * 64];     // [c][lane]  16 KB
  __shared__ float smin[8][64];
  __shared__ int   sidx[8][64];
  __shared__ int   bcomb[64];

  const int t    = threadIdx.x;
  const int lane = t & 63;
  const int w    = t >> 6;                       // 0..7
  const int blk  = blockIdx.x;                   // 1024 blocks
  const int b    = blk >> 4;                     // batch
  const int s0   = (blk & 15) << 6;              // spatial chunk base
  const size_t xbase = (size_t)b * (HD * HW) + s0;

  // ---- stage x into LDS: wave w loads c in [w*8, w*8+8), lanes sweep pos
  #pragma unroll
  for (int i = 0; i < 8; ++i) {
    const int c = w * 8 + i;
    xs[(c << 6) | lane] = x[xbase + (size_t)c * HW + lane];
  }
  __syncthreads();

  // ---- x_sq with numpy pairwise-8 order, no contraction (same values as
  // global, routed through LDS -- bit-identical)
  float xsq;
  {
    #pragma clang fp contract(off)
    float r[8];
    #pragma unroll
    for (int j = 0; j < 8; ++j) {
      const float v = xs[(j << 6) | lane];
      r[j] = v * v;
    }
    #pragma unroll
    for (int i = 8; i < HD; i += 8) {
      #pragma unroll
      for (int j = 0; j < 8; ++j) {
        const float v = xs[((i + j) << 6) | lane];
        r[j] = r[j] + v * v;
      }
    }
    xsq = ((r[0] + r[1]) + (r[2] + r[3])) + ((r[4] + r[5]) + (r[6] + r[7]));
  }

  // ---- this wave scans octets [w*8, w*8+8)  (codes [w*64, w*64+64))
  const int o0 = __builtin_amdgcn_readfirstlane(w) * 8;

  float bestd = __builtin_inff();
  int   besti = 0;
  #pragma unroll 1
  for (int o = o0; o < o0 + 8; ++o) {
    const float4* __restrict__ po =
        reinterpret_cast<const float4*>(ep + (size_t)o * 512);  // wave-uniform
    float a[8];
    #pragma unroll
    for (int j = 0; j < 8; ++j) a[j] = 0.f;
    #pragma unroll
    for (int c = 0; c < HD; ++c) {
      const float xc = xs[(c << 6) | lane];
      const float4 v0 = po[c * 2 + 0];
      const float4 v1 = po[c * 2 + 1];
      a[0] = fmaf(xc, v0.x, a[0]);   // sequential-c FMA == BLAS order; a == -2*cross
      a[1] = fmaf(xc, v0.y, a[1]);
      a[2] = fmaf(xc, v0.z, a[2]);
      a[3] = fmaf(xc, v0.w, a[3]);
      a[4] = fmaf(xc, v1.x, a[4]);
      a[5] = fmaf(xc, v1.y, a[5]);
      a[6] = fmaf(xc, v1.z, a[6]);
      a[7] = fmaf(xc, v1.w, a[7]);
    }
    const int kb = o * 8;
    #pragma unroll
    for (int j = 0; j < 8; ++j) {
      const float d = (xsq + esq[kb + j]) + a[j];  // == (xsq+esq) - 2*cross, bit-exact
      if (d < bestd) { bestd = d; besti = kb + j; } // strict < : first-index-wins
    }
  }

  // ---- combine the 8 waves' candidates per position (waves are ascending
  // k-ranges; strict < keeps the earlier wave on ties -> first-index-wins)
  smin[w][lane] = bestd;
  sidx[w][lane] = besti;
  __syncthreads();
  if (w == 0) {
    float bd = smin[0][lane];
    int   bi = sidx[0][lane];
    #pragma unroll
    for (int q = 1; q < 8; ++q) {
      const float d = smin[q][lane];
      if (d < bd) { bd = d; bi = sidx[q][lane]; }
    }
    bcomb[lane] = bi;
  }
  __syncthreads();

  // ---- gather winning codebook row, write in (b,c,h,w) layout.
  // lane sweeps spatial (contiguous) -> coalesced stores; wave splits c.
  const int idx = bcomb[lane];
  const float* __restrict__ eq = e + idx * HD;
  #pragma unroll
  for (int i = 0; i < 8; ++i) {
    const int c = w * 8 + i;
    out[xbase + (size_t)c * HW + lane] = eq[c];
  }
}

extern "C" void kernel_launch(void* const* d_in, const int* in_sizes, int n_in,
                              void* d_out, int out_size, void* d_ws, size_t ws_size,
                              hipStream_t stream) {
  const float* x = (const float*)d_in[0];   // (64, 64, 32, 32) fp32
  const float* e = (const float*)d_in[1];   // (512, 64) fp32
  float* ep  = (float*)d_ws;                // 512*64 floats packed -2*e
  float* esq = ep + NE * HD;                // 512 floats
  float* out = (float*)d_out;               // (64, 64, 32, 32) fp32

  vq_prep_kernel<<<72, 64, 0, stream>>>(e, ep, esq);
  vq_main_kernel<<<1024, 512, 0, stream>>>(x, ep, esq, e, out);
}